// Round 2
// baseline (6694.279 us; speedup 1.0000x reference)
//
#include <hip/hip_runtime.h>
#include <stdint.h>

typedef unsigned short u16;
using bf16x8 = __attribute__((ext_vector_type(8))) short;
using f32x4  = __attribute__((ext_vector_type(4))) float;

__device__ __forceinline__ float b2f(u16 v) {
  return __uint_as_float(((uint32_t)v) << 16);
}
__device__ __forceinline__ u16 f2b(float f) {
  uint32_t u = __float_as_uint(f);
  u = u + 0x7fffu + ((u >> 16) & 1u);
  return (u16)(u >> 16);
}
__device__ __forceinline__ float ldf(const void* p, size_t i, int f32) {
  return f32 ? ((const float*)p)[i] : b2f(((const u16*)p)[i]);
}
__device__ __forceinline__ float sigf(float x) {
  return __builtin_amdgcn_rcpf(1.f + __expf(-x));
}
__device__ __forceinline__ float tanhf_fast(float x) {
  x = fminf(fmaxf(x, -15.f), 15.f);
  float e = __expf(2.f * x);
  return (e - 1.f) * __builtin_amdgcn_rcpf(e + 1.f);
}

// ---------------------------------------------------------------------------
// Dtype detector: sample first 1024 u16s of x_enc (values ~N(0,1)).
// bf16 data -> ~100% plausible bf16 exponents; fp32 data -> ~58%.
// flag = 1 means inputs/outputs are fp32.
// ---------------------------------------------------------------------------
__global__ __launch_bounds__(1024) void k_detect(const u16* __restrict__ x, int* flag) {
  int tid = threadIdx.x;
  u16 v = x[tid];
  int e = (v >> 7) & 0xFF;
  int ok = (e >= 100 && e <= 140) ? 1 : 0;
#pragma unroll
  for (int o = 32; o > 0; o >>= 1) ok += __shfl_down(ok, o);
  __shared__ int s[16];
  if ((tid & 63) == 0) s[tid >> 6] = ok;
  __syncthreads();
  if (tid == 0) {
    int c = 0;
#pragma unroll
    for (int i = 0; i < 16; ++i) c += s[i];
    *flag = (c < 900) ? 1 : 0;
  }
}

// Generic convert-to-bf16 copy.
__global__ __launch_bounds__(256) void k_conv(u16* __restrict__ dst, const void* __restrict__ src,
                                              int n, const int* __restrict__ flagp) {
  int f32 = *flagp;
  int i = blockIdx.x * 256 + threadIdx.x;
  if (i < n) dst[i] = f32 ? f2b(((const float*)src)[i]) : ((const u16*)src)[i];
}

__global__ __launch_bounds__(256) void k_bias(float* __restrict__ bias, const void* b_ih,
                                              const void* b_hh, const int* __restrict__ flagp) {
  int f32 = *flagp;
  int n = blockIdx.x * 256 + threadIdx.x;
  if (n < 2048) bias[n] = ldf(b_ih, n, f32) + ldf(b_hh, n, f32);
}

// ---------------------------------------------------------------------------
// Generic NT GEMM: C[m,n] = sum_k A[m,k]*B[n,k].
// A: bf16 ws buffer. B: raw input (dtype per flag). 128x128 tile, 4 waves.
// EPI 0: pregates: Cb = bf16(acc + bias[n])
// EPI 1: pre:      Cb = bf16(tanh(acc))
// EPI 2: logits:   m=(t*32+b) -> out[b][t][n], store bf16 or fp32 per flag
// ---------------------------------------------------------------------------
template<int EPI>
__global__ __launch_bounds__(256) void gemm_bt(
    const u16* __restrict__ A, int lda,
    const void* __restrict__ B, int ldb,
    int M, int K,
    void* __restrict__ C,
    const float* __restrict__ bias,
    int ldc, const int* __restrict__ flagp)
{
  __shared__ __align__(16) u16 As[128 * 32];
  __shared__ __align__(16) u16 Bs[128 * 32];
  const int f32  = *flagp;
  const int tid  = threadIdx.x;
  const int lane = tid & 63;
  const int wv   = tid >> 6;
  const int wm   = (wv >> 1) * 64;
  const int wn   = (wv & 1) * 64;
  const int n0   = blockIdx.x * 128;
  const int m0   = blockIdx.y * 128;
  const int lr   = lane & 15;
  const int lk   = (lane >> 4) * 8;

  f32x4 acc[4][4] = {};

  for (int k0 = 0; k0 < K; k0 += 32) {
    __syncthreads();
#pragma unroll
    for (int c = 0; c < 2; ++c) {
      int idx = tid + c * 256;           // 0..511
      int row = idx >> 2;                // 0..127
      int col = (idx & 3) * 8;
      int ar = m0 + row; if (ar > M - 1) ar = M - 1;
      *(uint4*)&As[idx * 8] = *(const uint4*)&A[(size_t)ar * lda + k0 + col];
      int br = n0 + row;
      if (f32) {
        const float* bp = (const float*)B + (size_t)br * ldb + k0 + col;
        float4 x0 = *(const float4*)bp;
        float4 x1 = *(const float4*)(bp + 4);
        uint4 pk;
        pk.x = (uint32_t)f2b(x0.x) | ((uint32_t)f2b(x0.y) << 16);
        pk.y = (uint32_t)f2b(x0.z) | ((uint32_t)f2b(x0.w) << 16);
        pk.z = (uint32_t)f2b(x1.x) | ((uint32_t)f2b(x1.y) << 16);
        pk.w = (uint32_t)f2b(x1.z) | ((uint32_t)f2b(x1.w) << 16);
        *(uint4*)&Bs[idx * 8] = pk;
      } else {
        *(uint4*)&Bs[idx * 8] = *(const uint4*)((const u16*)B + (size_t)br * ldb + k0 + col);
      }
    }
    __syncthreads();
    bf16x8 af[4], bfr[4];
#pragma unroll
    for (int i = 0; i < 4; ++i) {
      af[i]  = *(const bf16x8*)&As[(wm + i * 16 + lr) * 32 + lk];
      bfr[i] = *(const bf16x8*)&Bs[(wn + i * 16 + lr) * 32 + lk];
    }
#pragma unroll
    for (int i = 0; i < 4; ++i)
#pragma unroll
      for (int j = 0; j < 4; ++j)
        acc[i][j] = __builtin_amdgcn_mfma_f32_16x16x32_bf16(af[i], bfr[j], acc[i][j], 0, 0, 0);
  }

#pragma unroll
  for (int i = 0; i < 4; ++i) {
#pragma unroll
    for (int j = 0; j < 4; ++j) {
#pragma unroll
      for (int r = 0; r < 4; ++r) {
        int m = m0 + wm + i * 16 + (lane >> 4) * 4 + r;
        int n = n0 + wn + j * 16 + lr;
        if (m < M) {
          float v = acc[i][j][r];
          if (EPI == 0) {
            ((u16*)C)[(size_t)m * ldc + n] = f2b(v + bias[n]);
          } else if (EPI == 1) {
            ((u16*)C)[(size_t)m * ldc + n] = f2b(tanhf_fast(v));
          } else {
            int tt = m >> 5, bb = m & 31;
            size_t off = (size_t)bb * 4064000 + (size_t)tt * 32000 + n;
            if (f32) ((float*)C)[off] = v;
            else     ((u16*)C)[off] = f2b(v);
          }
        }
      }
    }
  }
}

// ---------------------------------------------------------------------------
// Per-step recurrent gates GEMM (32x2048x1536) fused with LSTM cell.
// ---------------------------------------------------------------------------
__global__ __launch_bounds__(256) void k_step(
    const u16* __restrict__ inp,          // [32][1536] = [feed(1024) | h(512)]
    const u16* __restrict__ W3,           // [2048][1536] = [W_ih_feed | W_hh]
    const u16* __restrict__ pregates_t,   // [32][2048] bf16
    float* __restrict__ c_state,          // [32][512] fp32
    u16* __restrict__ inp_next,           // write h at cols 1024..1536
    u16* __restrict__ hctx_t)             // write h at cols 0..512
{
  const int tid  = threadIdx.x;
  const int lane = tid & 63;
  const int g    = tid >> 6;              // gate group 0..3 (i,f,g,o)
  const int c0   = blockIdx.x * 16;
  const int lr   = lane & 15;
  const int lk   = (lane >> 4) * 8;

  f32x4 acc0 = {}, acc1 = {};
  const u16* Ar = inp + lr * 1536 + lk;
  const u16* Br = W3 + (size_t)(g * 512 + c0 + lr) * 1536 + lk;
#pragma unroll 8
  for (int k0 = 0; k0 < 1536; k0 += 32) {
    bf16x8 a0 = *(const bf16x8*)(Ar + k0);
    bf16x8 a1 = *(const bf16x8*)(Ar + 16 * 1536 + k0);
    bf16x8 b  = *(const bf16x8*)(Br + k0);
    acc0 = __builtin_amdgcn_mfma_f32_16x16x32_bf16(a0, b, acc0, 0, 0, 0);
    acc1 = __builtin_amdgcn_mfma_f32_16x16x32_bf16(a1, b, acc1, 0, 0, 0);
  }

  __shared__ float gs[4][32][16];
#pragma unroll
  for (int r = 0; r < 4; ++r) {
    int mr = (lane >> 4) * 4 + r;
    gs[g][mr][lr]      = acc0[r] + b2f(pregates_t[mr * 2048 + g * 512 + c0 + lr]);
    gs[g][mr + 16][lr] = acc1[r] + b2f(pregates_t[(mr + 16) * 2048 + g * 512 + c0 + lr]);
  }
  __syncthreads();

  for (int e = tid; e < 512; e += 256) {
    int m = e >> 4, j = e & 15;
    int col = c0 + j;
    float iv = gs[0][m][j], fv = gs[1][m][j], gv = gs[2][m][j], ov = gs[3][m][j];
    float co = c_state[m * 512 + col];
    float cn = sigf(fv) * co + sigf(iv) * tanhf_fast(gv);
    float h  = sigf(ov) * tanhf_fast(cn);
    c_state[m * 512 + col] = cn;
    u16 hb = f2b(h);
    inp_next[m * 1536 + 1024 + col] = hb;
    hctx_t[m * 1536 + col] = hb;
  }
}

// ---------------------------------------------------------------------------
// Per-step attention (all operands are converted bf16 ws buffers).
// ---------------------------------------------------------------------------
__global__ __launch_bounds__(512) void k_att(
    const u16* __restrict__ inp_next,   // h at [b][1024+..]
    const u16* __restrict__ x_enc_k,    // [32][64][512]
    const u16* __restrict__ x_enc,      // [32][64][1024]
    const u16* __restrict__ W_trg,      // [512][512]
    const u16* __restrict__ b_trg,      // [512]
    const u16* __restrict__ W_att,      // [512]
    const u16* __restrict__ b_att,      // [1]
    u16* __restrict__ hctx_t,           // write ctx at cols 512..1536
    u16* __restrict__ feed_dst)         // write ctx at cols 0..1024
{
  const int b   = blockIdx.x;
  const int tid = threadIdx.x;
  __shared__ float hs[512], qs[512], wa[512], sc[64], wts[64];

  hs[tid] = b2f(inp_next[b * 1536 + 1024 + tid]);
  wa[tid] = b2f(W_att[tid]);
  __syncthreads();

  { // q[tid]
    float q = b2f(b_trg[tid]);
    const u16* wr = W_trg + tid * 512;
#pragma unroll 4
    for (int kk = 0; kk < 64; ++kk) {
      int k = kk * 8;
      bf16x8 w8 = *(const bf16x8*)(wr + k);
#pragma unroll
      for (int j = 0; j < 8; ++j)
        q += b2f((u16)w8[j]) * hs[k + j];
    }
    qs[tid] = q;
  }
  __syncthreads();

  const int wvv = tid >> 6, ln = tid & 63;
  for (int l = wvv; l < 64; l += 8) {
    float p = 0.f;
    const u16* xk = x_enc_k + ((size_t)b * 64 + l) * 512;
#pragma unroll
    for (int dd = 0; dd < 8; ++dd) {
      int d = ln + dd * 64;
      p += wa[d] * tanhf_fast(b2f(xk[d]) + qs[d]);
    }
#pragma unroll
    for (int o = 32; o > 0; o >>= 1) p += __shfl_down(p, o);
    if (ln == 0) sc[l] = p + b2f(b_att[0]);
  }
  __syncthreads();
  if (tid < 64) {
    float s = sc[tid];
    float mx = s;
#pragma unroll
    for (int o = 32; o > 0; o >>= 1) mx = fmaxf(mx, __shfl_xor(mx, o));
    float e = __expf(s - mx);
    float sm = e;
#pragma unroll
    for (int o = 32; o > 0; o >>= 1) sm += __shfl_xor(sm, o);
    wts[tid] = e * __builtin_amdgcn_rcpf(sm);
  }
  __syncthreads();
  {
    int d2 = tid * 2;
    float a0 = 0.f, a1 = 0.f;
    const u16* xe = x_enc + (size_t)b * 64 * 1024 + d2;
#pragma unroll 8
    for (int l = 0; l < 64; ++l) {
      float w = wts[l];
      uint32_t xx = *(const uint32_t*)(xe + (size_t)l * 1024);
      a0 += w * b2f((u16)(xx & 0xffffu));
      a1 += w * b2f((u16)(xx >> 16));
    }
    u16 cb0 = f2b(a0), cb1 = f2b(a1);
    feed_dst[b * 1536 + d2]     = cb0;
    feed_dst[b * 1536 + d2 + 1] = cb1;
    hctx_t[b * 1536 + 512 + d2]     = cb0;
    hctx_t[b * 1536 + 512 + d2 + 1] = cb1;
  }
}

// ---------------------------------------------------------------------------
// Setup kernels (dtype-aware)
// ---------------------------------------------------------------------------
__global__ __launch_bounds__(256) void k_gather(
    const int* __restrict__ x_train, const int* __restrict__ y_train,
    const void* __restrict__ word_emb, const void* __restrict__ attr_tab,
    u16* __restrict__ A_x, const int* __restrict__ flagp)
{
  int f32 = *flagp;
  int idx = blockIdx.x * 256 + threadIdx.x;
  if (idx >= 4064 * 1024) return;
  int m = idx >> 10, k = idx & 1023;
  int t = m >> 5, b = m & 31;
  u16 v;
  if (k < 512) {
    v = f2b(ldf(word_emb, (size_t)x_train[b * 128 + t] * 512 + k, f32));
  } else {
    int d = k - 512;
    float a = ldf(attr_tab, (size_t)y_train[b * 2] * 512 + d, f32) +
              ldf(attr_tab, (size_t)y_train[b * 2 + 1] * 512 + d, f32);
    v = f2b(a);
  }
  A_x[idx] = v;
}

__global__ __launch_bounds__(256) void k_w3(
    const void* __restrict__ W_ih, const void* __restrict__ W_hh,
    u16* __restrict__ W3, const int* __restrict__ flagp)
{
  int f32 = *flagp;
  int idx = blockIdx.x * 256 + threadIdx.x;   // 2048*1536
  if (idx >= 2048 * 1536) return;
  int n = idx / 1536, k = idx - n * 1536;
  float v = (k < 1024) ? ldf(W_ih, (size_t)n * 2048 + 1024 + k, f32)
                       : ldf(W_hh, (size_t)n * 512 + (k - 1024), f32);
  W3[idx] = f2b(v);
}

__global__ __launch_bounds__(256) void k_init(
    const void* __restrict__ dec_h0, const void* __restrict__ dec_c0,
    u16* __restrict__ inpA, float* __restrict__ c_state, const int* __restrict__ flagp)
{
  int f32 = *flagp;
  int idx = blockIdx.x * 256 + threadIdx.x;
  if (idx < 32 * 1536) {
    int m = idx / 1536, c = idx - m * 1536;
    inpA[idx] = (c < 1024) ? (u16)0 : f2b(ldf(dec_h0, m * 512 + (c - 1024), f32));
  }
  if (idx < 32 * 512) c_state[idx] = ldf(dec_c0, idx, f32);
}

// ---------------------------------------------------------------------------
extern "C" void kernel_launch(void* const* d_in, const int* in_sizes, int n_in,
                              void* d_out, int out_size, void* d_ws, size_t ws_size,
                              hipStream_t stream)
{
  const void* x_enc    = d_in[0];
  const void* x_enc_k  = d_in[1];
  const void* dec_h0   = d_in[2];
  const void* dec_c0   = d_in[3];
  const int* y_train   = (const int*)d_in[5];
  const int* x_train   = (const int*)d_in[6];
  const void* word_emb = d_in[7];
  const void* attr_tab = d_in[8];
  const void* W_ih     = d_in[9];
  const void* W_hh     = d_in[10];
  const void* b_ih     = d_in[11];
  const void* b_hh     = d_in[12];
  const void* W_trg    = d_in[13];
  const void* b_trg    = d_in[14];
  const void* W_att    = d_in[15];
  const void* b_att    = d_in[16];
  const void* W_cr     = d_in[17];
  const void* W_ro     = d_in[18];

  char* ws = (char*)d_ws;
  size_t off = 0;
  auto alloc = [&](size_t bytes) -> void* {
    void* p = ws + off;
    off += (bytes + 255) & ~(size_t)255;
    return p;
  };
  u16*   A_x      = (u16*)  alloc(4064ull * 1024 * 2);   // [t*32+b][x_emb|attr]
  u16*   pregates = (u16*)  alloc(4064ull * 2048 * 2);   // bf16 pre-gates
  u16*   W3       = (u16*)  alloc(2048ull * 1536 * 2);   // [W_ih_feed | W_hh]
  u16*   hctx     = (u16*)  alloc(4064ull * 1536 * 2);   // [h | ctx] per (t,b)
  u16*   pre_all  = (u16*)  alloc(4064ull * 512 * 2);
  u16*   cxe      = (u16*)  alloc(32ull * 64 * 1024 * 2);
  u16*   cxek     = (u16*)  alloc(32ull * 64 * 512 * 2);
  u16*   cW_trg   = (u16*)  alloc(512ull * 512 * 2);
  u16*   cb_trg   = (u16*)  alloc(512 * 2);
  u16*   cW_att   = (u16*)  alloc(512 * 2);
  u16*   cb_att   = (u16*)  alloc(16);
  float* bias     = (float*)alloc(2048 * 4);
  u16*   inpA     = (u16*)  alloc(32 * 1536 * 2);
  u16*   inpB     = (u16*)  alloc(32 * 1536 * 2);
  float* c_state  = (float*)alloc(32 * 512 * 4);
  int*   flag     = (int*)  alloc(256);

  k_detect<<<1, 1024, 0, stream>>>((const u16*)x_enc, flag);

  k_conv<<<(2097152 + 255) / 256, 256, 0, stream>>>(cxe, x_enc, 2097152, flag);
  k_conv<<<(1048576 + 255) / 256, 256, 0, stream>>>(cxek, x_enc_k, 1048576, flag);
  k_conv<<<(262144 + 255) / 256, 256, 0, stream>>>(cW_trg, W_trg, 262144, flag);
  k_conv<<<2, 256, 0, stream>>>(cb_trg, b_trg, 512, flag);
  k_conv<<<2, 256, 0, stream>>>(cW_att, W_att, 512, flag);
  k_conv<<<1, 256, 0, stream>>>(cb_att, b_att, 1, flag);
  k_bias<<<8, 256, 0, stream>>>(bias, b_ih, b_hh, flag);

  k_init<<<192, 256, 0, stream>>>(dec_h0, dec_c0, inpA, c_state, flag);
  k_gather<<<(4064 * 1024 + 255) / 256, 256, 0, stream>>>(x_train, y_train, word_emb, attr_tab, A_x, flag);
  k_w3<<<(2048 * 1536 + 255) / 256, 256, 0, stream>>>(W_ih, W_hh, W3, flag);

  // pre_gates = [x_emb|attr] @ W_ih[:, :1024].T + (b_ih + b_hh)
  gemm_bt<0><<<dim3(16, 32), 256, 0, stream>>>(
      A_x, 1024, W_ih, 2048, 4064, 1024, pregates, bias, 2048, flag);

  for (int t = 0; t < 127; ++t) {
    const u16* cur = (t & 1) ? inpB : inpA;
    u16* nxt = (t & 1) ? inpA : inpB;
    u16* hct = hctx + (size_t)t * 32 * 1536;
    k_step<<<32, 256, 0, stream>>>(cur, W3, pregates + (size_t)t * 32 * 2048,
                                   c_state, nxt, hct);
    k_att<<<32, 512, 0, stream>>>(nxt, cxek, cxe, cW_trg, cb_trg, cW_att, cb_att,
                                  hct, nxt);
  }

  // pre = tanh([h|ctx] @ W_cr.T)
  gemm_bt<1><<<dim3(4, 32), 256, 0, stream>>>(
      hctx, 1536, W_cr, 1536, 4064, 1536, pre_all, nullptr, 512, flag);
  // logits = pre @ W_ro.T  -> out[b][t][v]
  gemm_bt<2><<<dim3(250, 32), 256, 0, stream>>>(
      pre_all, 512, W_ro, 512, 4064, 512, d_out, nullptr, 32000, flag);
}